// Round 9
// baseline (219.011 us; speedup 1.0000x reference)
//
#include <hip/hip_runtime.h>
#include <stdint.h>

typedef unsigned short u16;
using bf16x8 = __attribute__((ext_vector_type(8))) short;
using f32x4  = __attribute__((ext_vector_type(4))) float;

#define NORM 0.03125f  // 1/sqrt(1024)

enum { M_PROJ = 0, M_EXP = 1, M_PV = 2, M_OUT = 3 };

__device__ __forceinline__ u16 f2bf(float f) {
  uint32_t u = __float_as_uint(f);
  return (u16)((u + 0x7FFFu + ((u >> 16) & 1u)) >> 16);  // RNE
}

__device__ __forceinline__ void gload_lds16(const void* g, void* lds) {
  __builtin_amdgcn_global_load_lds(
      (const __attribute__((address_space(1))) uint32_t*)g,
      (__attribute__((address_space(3))) uint32_t*)lds, 16, 0, 0);
}

// f32 -> bf16 elementwise, 4 elems/thread
__global__ void k_cvt(const float* __restrict__ in, u16* __restrict__ out, int n4) {
  int i = blockIdx.x * blockDim.x + threadIdx.x;
  if (i >= n4) return;
  float4 v = ((const float4*)in)[i];
  uint32_t lo = f2bf(v.x) | ((uint32_t)f2bf(v.y) << 16);
  uint32_t hi = f2bf(v.z) | ((uint32_t)f2bf(v.w) << 16);
  ((uint2*)out)[i] = make_uint2(lo, hi);
}

// transpose + convert the 4 weight matrices [1024x1024] f32 -> WT[n][k] bf16
__global__ void k_tc(const float* __restrict__ W0, const float* __restrict__ W1,
                     const float* __restrict__ W2, const float* __restrict__ W3,
                     u16* __restrict__ dst) {
  __shared__ float t[64][65];
  const float* W = blockIdx.z == 0 ? W0 : blockIdx.z == 1 ? W1 : blockIdx.z == 2 ? W2 : W3;
  u16* WT = dst + (size_t)blockIdx.z * (1024 * 1024);
  int c0 = blockIdx.x * 64, r0 = blockIdx.y * 64;
  int c = threadIdx.x & 63, q = threadIdx.x >> 6;
  for (int r = q; r < 64; r += 4) t[r][c] = W[(size_t)(r0 + r) * 1024 + c0 + c];
  __syncthreads();
  for (int r = q; r < 64; r += 4) WT[(size_t)(c0 + r) * 1024 + r0 + c] = f2bf(t[c][r]);
}

struct GArgs {
  const u16* A; const u16* B; int lda, ldb; long long bstrideB; int K;
  const float* bias; const float* adj; float* dpart; const float* dpart_r;
  void* C; int ldc;
  const u16* A1; const u16* B1; const u16* B2;
  const float* bias1; const float* bias2; void* C1; void* C2;
};

// ---------------- EXP: m201-faithful 256x256 8-wave phase kernel ----------
// 256x256 tile, BK=64, 8 waves (2m x 4n), per-wave C = 128x64 (acc[8][4]).
// LDS 128KB = 2 dbuf x { A[2kh][256][32] | B[2kh][256][32] }.
// Swizzle: byte col ^ ((row&8)<<2), 16B granules; staged with linear dest +
// inverse-swizzled global source (involution).
// Per phase (h,kh): {8 ds_read | stage 1 half-unit | s_barrier | setprio1
// 16 MFMA setprio0 | s_barrier}. vmcnt(4) ONCE per tile at ph1 (leaves the
// next k-half pair in flight; never drains mid-loop). NO sched_barrier, NO
// manual lgkmcnt (compiler data-deps order ds_read->MFMA precisely).
__global__ __launch_bounds__(512, 2) void gemm8exp(
    const u16* __restrict__ Qb, const u16* __restrict__ Kb,
    const float* __restrict__ adj, float* __restrict__ dpart,
    u16* __restrict__ E) {
  __shared__ __align__(16) u16 sm[65536];  // 128 KB

  const int tid = threadIdx.x, lane = tid & 63, wid = tid >> 6;
  const int wm = wid >> 2, wn = wid & 3;
  const int m0 = blockIdx.x * 256;
  const int n0 = blockIdx.y * 256;
  const int b = m0 >> 11;
  const u16* Bp = Kb + (size_t)b * 2097152;
  const int NT = 16;  // K=1024 / 64

  f32x4 acc[8][4] = {};

  auto stage = [&](const u16* src, int r0, int kc, int dst_u16) {
#pragma unroll
    for (int j = 0; j < 2; ++j) {
      int row = wid * 16 + j * 128 + (lane >> 2);
      int cb = (lane & 3) * 16;
      int csw = cb ^ ((row & 8) << 2);
      gload_lds16(src + (size_t)(r0 + row) * 1024 + kc + (csw >> 1),
                  (void*)&sm[dst_u16 + wid * 512 + j * 4096]);
    }
  };
  auto stA = [&](int v, int kh) {
    stage(Qb, m0, v * 64 + kh * 32, (v & 1) * 32768 + kh * 8192);
  };
  auto stB = [&](int v, int kh) {
    stage(Bp, n0, v * 64 + kh * 32, (v & 1) * 32768 + 16384 + kh * 8192);
  };

  // prologue: tile0 (k0,k1), tile1 (k0); vmcnt(8) => tile0-k0 resident
  stA(0, 0); stB(0, 0); stA(0, 1); stB(0, 1);
  stA(1, 0); stB(1, 0);
  asm volatile("s_waitcnt vmcnt(8)" ::: "memory");
  __builtin_amdgcn_s_barrier();

  const int cb = (lane >> 4) * 16;
  for (int u = 0; u < NT; ++u) {
    const int base = (u & 1) * 32768;
#pragma unroll
    for (int ph = 0; ph < 4; ++ph) {
      const int h = ph & 1, kh = ph >> 1;
      bf16x8 af[4], bfr[4];
#pragma unroll
      for (int m = 0; m < 4; ++m) {
        int row = wm * 128 + h * 64 + m * 16 + (lane & 15);
        af[m] = *(const bf16x8*)__builtin_assume_aligned(
            &sm[base + kh * 8192 + row * 32 + ((cb ^ ((row & 8) << 2)) >> 1)], 16);
      }
#pragma unroll
      for (int n = 0; n < 4; ++n) {
        int row = wn * 64 + n * 16 + (lane & 15);
        bfr[n] = *(const bf16x8*)__builtin_assume_aligned(
            &sm[base + 16384 + kh * 8192 + row * 32 + ((cb ^ ((row & 8) << 2)) >> 1)], 16);
      }
      // stage schedule: ph0: A-k1(u+1); ph1: B-k1(u+1)+vmcnt; ph2: A-k0(u+2); ph3: B-k0(u+2)
      if (ph == 0) {
        if (u + 1 < NT) stA(u + 1, 1);
      } else if (ph == 1) {
        if (u + 1 < NT) {
          stB(u + 1, 1);
          asm volatile("s_waitcnt vmcnt(4)" ::: "memory");
        } else {
          asm volatile("s_waitcnt vmcnt(0)" ::: "memory");
        }
      } else if (ph == 2) {
        if (u + 2 < NT) stA(u + 2, 0);
      } else {
        if (u + 2 < NT) stB(u + 2, 0);
      }
      __builtin_amdgcn_s_barrier();
      __builtin_amdgcn_s_setprio(1);
#pragma unroll
      for (int m = 0; m < 4; ++m)
#pragma unroll
        for (int n = 0; n < 4; ++n)
          acc[h * 4 + m][n] = __builtin_amdgcn_mfma_f32_16x16x32_bf16(
              af[m], bfr[n], acc[h * 4 + m][n], 0, 0, 0);
      __builtin_amdgcn_s_setprio(0);
      __builtin_amdgcn_s_barrier();
    }
  }

  // epilogue: E = exp(acc*NORM + adj), partial row sums
  const int lr = lane >> 4, lc = lane & 15;
  float esum[8][4];
#pragma unroll
  for (int i = 0; i < 8; ++i)
#pragma unroll
    for (int r = 0; r < 4; ++r) esum[i][r] = 0.f;
#pragma unroll
  for (int i = 0; i < 8; ++i) {
    int rowo = (i >> 2) * 64 + (i & 3) * 16;
#pragma unroll
    for (int n = 0; n < 4; ++n) {
      int gcol = n0 + wn * 64 + n * 16 + lc;
#pragma unroll
      for (int r = 0; r < 4; ++r) {
        int grow = m0 + wm * 128 + rowo + lr * 4 + r;
        float z = acc[i][n][r] * NORM + adj[(size_t)grow * 2048 + gcol];
        float e = __expf(z);
        E[(size_t)grow * 2048 + gcol] = f2bf(e);
        esum[i][r] += e;
      }
    }
  }
  int pidx = blockIdx.y * 4 + wn;  // 8 t-tiles x 4 wave-cols = 32 partials
#pragma unroll
  for (int i = 0; i < 8; ++i) {
    int rowo = (i >> 2) * 64 + (i & 3) * 16;
#pragma unroll
    for (int r = 0; r < 4; ++r) {
      float s = esum[i][r];
      s += __shfl_xor(s, 1); s += __shfl_xor(s, 2);
      s += __shfl_xor(s, 4); s += __shfl_xor(s, 8);
      if (lc == 0)
        dpart[(size_t)pidx * 8192 + m0 + wm * 128 + rowo + lr * 4 + r] = s;
    }
  }
}

// ---------------- PROJ / PV / OUT: r8 occupancy-first 128x128 kernel ------
template <int MODE>
__global__ __launch_bounds__(256, 4) void gemm_occ(GArgs g) {
  __shared__ __align__(16) u16 As[128 * 64];
  __shared__ __align__(16) u16 Bs[128 * 64];

  const int tid = threadIdx.x;
  const int lane = tid & 63;
  const int wid = tid >> 6;
  const int wr = wid >> 1, wc = wid & 1;

  const int m0 = blockIdx.x * 128;
  const int n0 = blockIdx.y * 128;
  const int b = m0 >> 11;  // 2048 rows per batch

  const u16* A = g.A; const u16* B = g.B;
  const float* bias = g.bias; void* C = g.C;
  int zmode = 0;
  if constexpr (MODE == M_PROJ) {
    int z = blockIdx.z; zmode = z;
    if (z == 1) { A = g.A1; B = g.B1; bias = g.bias1; C = g.C1; }
    else if (z == 2) { A = g.A1; B = g.B2; bias = g.bias2; C = g.C2; }
  }
  const int lda = g.lda, ldb = g.ldb, K = g.K;
  const u16* Bp = B + (size_t)b * g.bstrideB;

  f32x4 acc[4][4] = {};

  const int ric = lane >> 3;         // row within 8-row chunk
  const int c8 = (lane & 7) * 8;     // u16 col granule (16B)

  const int fr = lane & 15;
  const int hi = lane >> 4;

  for (int kt = 0; kt < K; kt += 64) {
#pragma unroll
    for (int c = 0; c < 4; ++c) {
      int ch = wid * 4 + c;          // 16 chunks of 8 rows x 128B
      int row = ch * 8 + ric;
      int swc = c8 ^ ((row & 7) << 3);  // inverse-swizzled source col
      gload_lds16(A + (size_t)(m0 + row) * lda + kt + swc, (void*)&As[ch * 512]);
      gload_lds16(Bp + (size_t)(n0 + row) * ldb + kt + swc, (void*)&Bs[ch * 512]);
    }
    __syncthreads();
#pragma unroll
    for (int kk = 0; kk < 64; kk += 32) {
      bf16x8 af[4], bfr[4];
#pragma unroll
      for (int m = 0; m < 4; ++m) {
        int row = wr * 64 + m * 16 + fr;
        af[m] = *(const bf16x8*)__builtin_assume_aligned(
            &As[row * 64 + ((kk + hi * 8) ^ ((row & 7) << 3))], 16);
      }
#pragma unroll
      for (int n = 0; n < 4; ++n) {
        int row = wc * 64 + n * 16 + fr;
        bfr[n] = *(const bf16x8*)__builtin_assume_aligned(
            &Bs[row * 64 + ((kk + hi * 8) ^ ((row & 7) << 3))], 16);
      }
#pragma unroll
      for (int m = 0; m < 4; ++m)
#pragma unroll
        for (int n = 0; n < 4; ++n)
          acc[m][n] = __builtin_amdgcn_mfma_f32_16x16x32_bf16(af[m], bfr[n], acc[m][n], 0, 0, 0);
    }
    __syncthreads();
  }

  // C layout (m89-verified): col = lane&15, row = (lane>>4)*4 + reg
  const int lr = lane >> 4;
  const int lc = lane & 15;

  if constexpr (MODE == M_PROJ) {
    if (zmode < 2) {
      u16* Cc = (u16*)C;
#pragma unroll
      for (int m = 0; m < 4; ++m)
#pragma unroll
        for (int n = 0; n < 4; ++n) {
          int gcol = n0 + wc * 64 + n * 16 + lc;
          float bv = bias[gcol];
#pragma unroll
          for (int r = 0; r < 4; ++r) {
            int grow = m0 + wr * 64 + m * 16 + lr * 4 + r;
            Cc[(size_t)grow * g.ldc + gcol] = f2bf(acc[m][n][r] + bv);
          }
        }
    } else {  // V: store transposed Vt[b][d][t]
      u16* Cc = (u16*)C;
#pragma unroll
      for (int m = 0; m < 4; ++m) {
        int grow0 = m0 + wr * 64 + m * 16 + lr * 4;
        int t0 = grow0 & 2047;
#pragma unroll
        for (int n = 0; n < 4; ++n) {
          int gcol = n0 + wc * 64 + n * 16 + lc;
          float bv = bias[gcol];
          ushort4 pk = make_ushort4(f2bf(acc[m][n][0] + bv), f2bf(acc[m][n][1] + bv),
                                    f2bf(acc[m][n][2] + bv), f2bf(acc[m][n][3] + bv));
          *(ushort4*)&Cc[((size_t)b * 1024 + gcol) * 2048 + t0] = pk;
        }
      }
    }
  } else if constexpr (MODE == M_PV) {
    __shared__ float dinv[128];
    if (tid < 128) {
      float s = 0.f;
#pragma unroll
      for (int t = 0; t < 32; ++t) s += g.dpart_r[(size_t)t * 8192 + m0 + tid];
      dinv[tid] = 1.0f / s;
    }
    __syncthreads();
    u16* Cc = (u16*)C;
#pragma unroll
    for (int m = 0; m < 4; ++m)
#pragma unroll
      for (int n = 0; n < 4; ++n) {
        int gcol = n0 + wc * 64 + n * 16 + lc;
#pragma unroll
        for (int r = 0; r < 4; ++r) {
          int lrow = wr * 64 + m * 16 + lr * 4 + r;
          Cc[(size_t)(m0 + lrow) * g.ldc + gcol] = f2bf(acc[m][n][r] * dinv[lrow]);
        }
      }
  } else {  // M_OUT: f32 + bias
    float* Cc = (float*)C;
#pragma unroll
    for (int m = 0; m < 4; ++m)
#pragma unroll
      for (int n = 0; n < 4; ++n) {
        int gcol = n0 + wc * 64 + n * 16 + lc;
        float bv = bias[gcol];
#pragma unroll
        for (int r = 0; r < 4; ++r) {
          int grow = m0 + wr * 64 + m * 16 + lr * 4 + r;
          Cc[(size_t)grow * g.ldc + gcol] = acc[m][n][r] + bv;
        }
      }
  }
}

extern "C" void kernel_launch(void* const* d_in, const int* in_sizes, int n_in,
                              void* d_out, int out_size, void* d_ws, size_t ws_size,
                              hipStream_t stream) {
  const float* x   = (const float*)d_in[0];
  const float* y   = (const float*)d_in[1];
  const float* adj = (const float*)d_in[2];
  const float* Wq  = (const float*)d_in[3];
  const float* bq  = (const float*)d_in[4];
  const float* Wk  = (const float*)d_in[5];
  const float* bk  = (const float*)d_in[6];
  const float* Wv  = (const float*)d_in[7];
  const float* bv  = (const float*)d_in[8];
  const float* Wo  = (const float*)d_in[9];
  const float* bo  = (const float*)d_in[10];
  float* out = (float*)d_out;

  char* ws = (char*)d_ws;
  if (ws_size < 143654912ULL) return;  // need ~137 MB
  u16* xb = (u16*)(ws);                 // [8192][1024] bf16
  u16* yb = (u16*)(ws + 16777216);      // [8192][1024]
  u16* WT = (u16*)(ws + 33554432);      // 4 x [1024][1024] (transposed)
  u16* Qb = (u16*)(ws + 41943040);      // [8192][1024]
  u16* Kb = (u16*)(ws + 58720256);      // [8192][1024]
  u16* Vt = (u16*)(ws + 75497472);      // [4][1024][2048] (V transposed)
  u16* E  = (u16*)(ws + 92274688);      // [8192][2048] unnormalized exp
  float* dpart = (float*)(ws + 125829120);  // [32][8192] partial denoms
  u16* tmpb = (u16*)(ws + 126877696);   // [8192][1024] attention output

  u16* WqT = WT;
  u16* WkT = WT + 1048576;
  u16* WvT = WT + 2097152;
  u16* WoT = WT + 3145728;

  k_cvt<<<8192, 256, 0, stream>>>(x, xb, 2097152);
  k_cvt<<<8192, 256, 0, stream>>>(y, yb, 2097152);
  k_tc<<<dim3(16, 16, 4), 256, 0, stream>>>(Wq, Wk, Wv, Wo, WT);

  GArgs ga;
  // fused Q/K/V projections (z selects); 64x8x3 = 1536 blocks
  ga.A = xb; ga.B = WqT; ga.lda = 1024; ga.ldb = 1024; ga.bstrideB = 0; ga.K = 1024;
  ga.bias = bq; ga.adj = nullptr; ga.dpart = nullptr; ga.dpart_r = nullptr;
  ga.C = Qb; ga.ldc = 1024;
  ga.A1 = yb; ga.B1 = WkT; ga.B2 = WvT; ga.bias1 = bk; ga.bias2 = bv;
  ga.C1 = Kb; ga.C2 = Vt;
  gemm_occ<M_PROJ><<<dim3(64, 8, 3), 256, 0, stream>>>(ga);

  // E = exp(Q@K^T * norm + adj) via 256^2 8-phase kernel; 32x8 = 256 blocks
  gemm8exp<<<dim3(32, 8), 512, 0, stream>>>(Qb, Kb, adj, dpart, E);

  // tmp = (E @ V) / denom; 64x8 = 512 blocks
  GArgs gp = {};
  gp.A = E; gp.B = Vt; gp.lda = 2048; gp.ldb = 2048; gp.bstrideB = 2097152LL; gp.K = 2048;
  gp.bias = nullptr; gp.adj = nullptr; gp.dpart = nullptr; gp.dpart_r = dpart;
  gp.C = tmpb; gp.ldc = 1024;
  gemm_occ<M_PV><<<dim3(64, 8), 256, 0, stream>>>(gp);

  // out = tmp @ Wo + bo  (f32); 64x8 = 512 blocks
  GArgs go = {};
  go.A = tmpb; go.B = WoT; go.lda = 1024; go.ldb = 1024; go.bstrideB = 0; go.K = 1024;
  go.bias = bo; go.adj = nullptr; go.dpart = nullptr; go.dpart_r = nullptr;
  go.C = out; go.ldc = 1024;
  gemm_occ<M_OUT><<<dim3(64, 8), 256, 0, stream>>>(go);
}